// Round 10
// baseline (71.067 us; speedup 1.0000x reference)
//
#include <hip/hip_runtime.h>
#include <math.h>

#define NROWS 8192
#define NK    4096
#define NE    64

typedef _Float16 f16x8 __attribute__((ext_vector_type(8)));  // 4 VGPRs
typedef float    f32x4 __attribute__((ext_vector_type(4)));

// f32 -> (hi,lo) f16 pair, elementwise for 8 values in two float4s
#define CVT8(H, L, V0, V1)                                            \
  do {                                                                \
    H[0] = (_Float16)V0.x; L[0] = (_Float16)(V0.x - (float)H[0]);     \
    H[1] = (_Float16)V0.y; L[1] = (_Float16)(V0.y - (float)H[1]);     \
    H[2] = (_Float16)V0.z; L[2] = (_Float16)(V0.z - (float)H[2]);     \
    H[3] = (_Float16)V0.w; L[3] = (_Float16)(V0.w - (float)H[3]);     \
    H[4] = (_Float16)V1.x; L[4] = (_Float16)(V1.x - (float)H[4]);     \
    H[5] = (_Float16)V1.y; L[5] = (_Float16)(V1.y - (float)H[5]);     \
    H[6] = (_Float16)V1.z; L[6] = (_Float16)(V1.z - (float)H[6]);     \
    H[7] = (_Float16)V1.w; L[7] = (_Float16)(V1.w - (float)H[7]);     \
  } while (0)

// async global -> LDS, 16B per lane (lds dest = uniform base + lane*16)
__device__ __forceinline__ void gload16(const void* g, void* l) {
  __builtin_amdgcn_global_load_lds(
      (const __attribute__((address_space(1))) unsigned int*)g,
      (__attribute__((address_space(3))) unsigned int*)l, 16, 0, 0);
}

// ---------------------------------------------------------------------------
// Kernel 0: arrange W into MFMA-fragment-linear f16 hi/lo arrays + zero imp.
// Element ((ksg*4 + nt)*64 + lane)*8 + j holds
//   f16( W[nt*16 + (lane&15)][ksg*32 + (lane>>4)*8 + j] ), ksg = 0..127.
// (verified rounds 4-9, absmax 0)
// ---------------------------------------------------------------------------
__global__ __launch_bounds__(256) void k_prep(const float* __restrict__ W,
                                              _Float16* __restrict__ Whi,
                                              _Float16* __restrict__ Wlo,
                                              float* __restrict__ imp) {
  const int idx = blockIdx.x * 256 + threadIdx.x;   // 0 .. 262143
  if (idx < NE) imp[idx] = 0.f;
  const int j    = idx & 7;
  const int lane = (idx >> 3) & 63;
  const int nt   = (idx >> 9) & 3;
  const int ksg  = idx >> 11;                        // 0..127
  const int e = nt * 16 + (lane & 15);
  const int k = ksg * 32 + (lane >> 4) * 8 + j;
  const float w = W[(size_t)e * NK + k];
  const _Float16 wh = (_Float16)w;
  const _Float16 wl = (_Float16)(w - (float)wh);
  Whi[idx] = wh;
  Wlo[idx] = wl;
}

// ---------------------------------------------------------------------------
// Kernel 1 (FUSED, split-N): grid = 256 (1 block/CU), block = 512 (8 waves).
// Wave (mi,ni) = (wv>>2, wv&3) computes ONE 16x16 output tile over FULL K
// -> acc in 8 VGPRs, no cross-wave reduction, no big register working set
// (rounds 7-9 showed the allocator defeats register staging; this needs none).
// x: triple-buffered LDS chunks (128 k) via global_load_lds; row stride 144 B
//    (9 x 16B units, 1 pad) -> conflict-free ds_read_b128 fragment reads.
// W: fragment-linear hi/lo regs loaded per chunk; compiler's auto-vmcnt for
//    the W-reg MFMA dependency transitively guarantees stage(c+1) completion
//    (stage(c+1) is older in the vmem queue) -> raw s_barrier, no drain.
// ---------------------------------------------------------------------------
#define STAGE(cc)                                                             \
  if (wv < 6) {                                                               \
    _Pragma("unroll")                                                         \
    for (int jj = 0; jj < 3; ++jj) {                                          \
      const int j  = wv * 3 + jj;            /* 0..17: 1KB units */           \
      const int t  = j * 64 + lane;          /* 16B unit 0..1151 */           \
      const int rr = t / 9;                  /* ksl*32 + row     */           \
      const int u  = t - rr * 9;             /* 0..8 (8 = pad)   */           \
      const int ksl_ = rr >> 5, r_ = rr & 31;                                 \
      const int uu = (u < 8) ? u : 7;        /* pad -> dup, never read */     \
      const float* gsrc = x + (size_t)(rbase + r_) * NK +                     \
                          ((cc) * 128 + ksl_ * 32 + uu * 4);                  \
      gload16(gsrc, (char*)&X[(cc) % 3][0][0][0] + j * 1024);                 \
    }                                                                         \
  }

__global__ __launch_bounds__(512) void k_fused(const float* __restrict__ x,
                                               const _Float16* __restrict__ Whi,
                                               const _Float16* __restrict__ Wlo,
                                               float* __restrict__ out,
                                               float* __restrict__ imp) {
  __shared__ float X[3][4][32][36];   // 55.3 KB; aliased as logit/simp after

  const int tid  = threadIdx.x;
  const int lane = tid & 63;
  const int wv   = __builtin_amdgcn_readfirstlane(tid >> 6);  // 0..7
  const int mi   = wv >> 2;            // M-tile (0..1)
  const int ni   = wv & 3;             // N-tile (0..3)
  const int l15  = lane & 15;
  const int lhi  = lane >> 4;
  const int rbase = blockIdx.x * 32;
  const int mrow  = mi * 16 + l15;

  // ---- prologue: stage chunks 0,1; full drain once ----
  STAGE(0);
  STAGE(1);
  __syncthreads();

  f32x4 accp = (f32x4){0.f, 0.f, 0.f, 0.f};
  f32x4 accq = (f32x4){0.f, 0.f, 0.f, 0.f};

#pragma unroll 1
  for (int c = 0; c < 32; ++c) {      // 32 chunks x 128 k
    // W fragments for this chunk -> registers (L2/L1-resident, coalesced)
    f16x8 wh[4], wl[4];
#pragma unroll
    for (int ksl = 0; ksl < 4; ++ksl) {
      const size_t fo = (((size_t)(c * 4 + ksl) * 4 + ni) * 64 + lane) * 8;
      wh[ksl] = *(const f16x8*)(Whi + fo);
      wl[ksl] = *(const f16x8*)(Wlo + fo);
    }
    if (c + 2 < 32) { STAGE(c + 2); }

    const float (*Xc)[32][36] = X[c % 3];
#pragma unroll
    for (int ksl = 0; ksl < 4; ++ksl) {
      const float4 xa = *(const float4*)&Xc[ksl][mrow][lhi * 8];
      const float4 xb = *(const float4*)&Xc[ksl][mrow][lhi * 8 + 4];
      f16x8 ah, al;
      CVT8(ah, al, xa, xb);
      accp = __builtin_amdgcn_mfma_f32_16x16x32_f16(ah, wh[ksl], accp, 0, 0, 0);
      accq = __builtin_amdgcn_mfma_f32_16x16x32_f16(ah, wl[ksl], accq, 0, 0, 0);
      accq = __builtin_amdgcn_mfma_f32_16x16x32_f16(al, wh[ksl], accq, 0, 0, 0);
    }

    __builtin_amdgcn_s_barrier();        // raw: no vmcnt drain (keep stages in flight)
    __builtin_amdgcn_sched_barrier(0);   // rule 18: pin code motion at barrier
  }

  __syncthreads();                       // all compute done; X reusable
  float* logitp = &X[0][0][0][0];        // [32][64] logits
  float* simpp  = logitp + 32 * 64;      // [8][64] importance partials

  const f32x4 accf = accp + accq;
#pragma unroll
  for (int r = 0; r < 4; ++r)
    logitp[(mi * 16 + lhi * 4 + r) * 64 + ni * 16 + l15] = accf[r];
  __syncthreads();

  // ---- softmax/top-2/renorm (verified rounds 6-9): wave wv rows wv*4..+4 --
  float impacc = 0.f;
#pragma unroll 1
  for (int i = 0; i < 4; ++i) {
    const int rl  = wv * 4 + i;
    const int row = rbase + rl;
    const float lg = logitp[rl * 64 + lane];

    float m = lg;
#pragma unroll
    for (int d = 1; d < 64; d <<= 1) m = fmaxf(m, __shfl_xor(m, d));
    float p = expf(lg - m);
    float s = p;
#pragma unroll
    for (int d = 1; d < 64; d <<= 1) s += __shfl_xor(s, d);
    const float gate = p / s;
    impacc += gate;

    const unsigned long long key =
        ((unsigned long long)__float_as_uint(gate) << 32) | (unsigned)(63 - lane);
    unsigned long long k1 = key;
#pragma unroll
    for (int d = 1; d < 64; d <<= 1) {
      unsigned long long o = __shfl_xor(k1, d);
      if (o > k1) k1 = o;
    }
    const int e1 = 63 - (int)(k1 & 63ull);
    unsigned long long k2 = (lane == e1) ? 0ull : key;
#pragma unroll
    for (int d = 1; d < 64; d <<= 1) {
      unsigned long long o = __shfl_xor(k2, d);
      if (o > k2) k2 = o;
    }
    const int e2 = 63 - (int)(k2 & 63ull);

    if (lane == 0) {
      const float g1 = __uint_as_float((unsigned)(k1 >> 32));
      const float g2 = __uint_as_float((unsigned)(k2 >> 32));
      const float tt  = expf(g2 - g1);          // g1 >= g2
      const float inv = 1.f / (1.f + tt);
      out[(size_t)row * 2]     = inv;
      out[(size_t)row * 2 + 1] = tt * inv;
      out[(size_t)NROWS * 2 + row * 2]     = (float)e1;
      out[(size_t)NROWS * 2 + row * 2 + 1] = (float)e2;
    }
  }
  simpp[wv * 64 + lane] = impacc;
  __syncthreads();

  if (tid < NE) {
    const float v =
        (((simpp[0 * 64 + tid] + simpp[1 * 64 + tid]) +
          (simpp[2 * 64 + tid] + simpp[3 * 64 + tid])) +
         ((simpp[4 * 64 + tid] + simpp[5 * 64 + tid]) +
          (simpp[6 * 64 + tid] + simpp[7 * 64 + tid])));
    atomicAdd(&imp[tid], v);
  }
}

// ---------------------------------------------------------------------------
// Kernel 2: aux loss from importance vector (1 wave).
// ---------------------------------------------------------------------------
__global__ void k_aux(const float* __restrict__ imp, float* __restrict__ out) {
  const int lane = threadIdx.x;  // 64 threads
  const float v = imp[lane];
  float s = v;
#pragma unroll
  for (int d = 1; d < 64; d <<= 1) s += __shfl_xor(s, d);
  const float mean = s / 64.f;
  const float dv = v - mean;
  float sq = dv * dv;
#pragma unroll
  for (int d = 1; d < 64; d <<= 1) sq += __shfl_xor(sq, d);
  const float stdv = sqrtf(sq / 63.f);  // unbiased (E-1)
  const float r = stdv / (mean + 1e-6f);
  if (lane == 0) out[(size_t)NROWS * 4] = r * r;  // d_out[32768]
}

// ---------------------------------------------------------------------------
extern "C" void kernel_launch(void* const* d_in, const int* in_sizes, int n_in,
                              void* d_out, int out_size, void* d_ws, size_t ws_size,
                              hipStream_t stream) {
  const float* x = (const float*)d_in[0];
  const float* W = (const float*)d_in[1];
  float* out  = (float*)d_out;
  _Float16* Whi = (_Float16*)d_ws;                 // 512 KB
  _Float16* Wlo = Whi + (size_t)NE * NK;           // 512 KB
  float* imp  = (float*)(Wlo + (size_t)NE * NK);   // 64 f32

  hipLaunchKernelGGL(k_prep,  dim3(1024), dim3(256), 0, stream, W, Whi, Wlo, imp);
  hipLaunchKernelGGL(k_fused, dim3(256),  dim3(512), 0, stream, x, Whi, Wlo, out, imp);
  hipLaunchKernelGGL(k_aux,   dim3(1),    dim3(64),  0, stream, imp, out);
}

// Round 11
// 53.845 us; speedup vs baseline: 1.3198x; 1.3198x over previous
//
#include <hip/hip_runtime.h>
#include <math.h>

#define NROWS 8192
#define NK    4096
#define NE    64
#define NSEG  8     // K segments of 512, one per block

typedef _Float16 f16x8 __attribute__((ext_vector_type(8)));  // 4 VGPRs
typedef float    f32x4 __attribute__((ext_vector_type(4)));

// f32 -> (hi,lo) f16 pair, elementwise for 8 values in two float4s
#define CVT8(H, L, V0, V1)                                            \
  do {                                                                \
    H[0] = (_Float16)V0.x; L[0] = (_Float16)(V0.x - (float)H[0]);     \
    H[1] = (_Float16)V0.y; L[1] = (_Float16)(V0.y - (float)H[1]);     \
    H[2] = (_Float16)V0.z; L[2] = (_Float16)(V0.z - (float)H[2]);     \
    H[3] = (_Float16)V0.w; L[3] = (_Float16)(V0.w - (float)H[3]);     \
    H[4] = (_Float16)V1.x; L[4] = (_Float16)(V1.x - (float)H[4]);     \
    H[5] = (_Float16)V1.y; L[5] = (_Float16)(V1.y - (float)H[5]);     \
    H[6] = (_Float16)V1.z; L[6] = (_Float16)(V1.z - (float)H[6]);     \
    H[7] = (_Float16)V1.w; L[7] = (_Float16)(V1.w - (float)H[7]);     \
  } while (0)

// ---------------------------------------------------------------------------
// Kernel 1: partial logits. grid = 256 (32 row-groups x 8 K-segs), block 512.
// Per block: convert its W K-slice (64 x 512 f32, L3-hot) into fragment-
// linear f16 hi/lo LDS (128 KB) -- removes the k_prep kernel AND turns the
// in-loop W traffic into ds_read_b128 (cannot be latency-sunk by the
// allocator, well-pipelined via lgkmcnt; rounds 6-10 showed register W loads
// are the serialized-latency wall). Wave wv: rows rg*256 + wv*32 .. +32,
// two 16-row M-tiles sharing B-frags, K-seg 512 (bit-identical to round 5).
// In-loop VMEM: only 4 x float4 loads (depth-2 prefetch).
// 128 KB LDS caps occupancy at 2 waves/EU -> allocator gets a 256-VGPR budget.
// Block 0 also zeroes imp/cnt (ordered before k_soft by the kernel boundary).
// ---------------------------------------------------------------------------
__global__ __launch_bounds__(512)
__attribute__((amdgpu_waves_per_eu(2, 2)))
void k_main(const float* __restrict__ x,
            const float* __restrict__ W,
            float* __restrict__ part,
            float* __restrict__ imp,
            unsigned* __restrict__ cnt) {
  __shared__ f16x8 WH[16][4][64];   // 64 KB: [kstep][nt][lane] hi frags
  __shared__ f16x8 WL[16][4][64];   // 64 KB: lo frags

  const int tid  = threadIdx.x;
  const int lane = tid & 63;
  const int wv   = __builtin_amdgcn_readfirstlane(tid >> 6);  // 0..7
  const int rg   = blockIdx.x >> 3;    // 0..31 row-group (256 rows)
  const int seg  = blockIdx.x & 7;     // K-segment
  const int l15  = lane & 15;
  const int lhi  = lane >> 4;
  const int rbase = rg * 256 + wv * 32;
  const int k0    = seg * 512;

  if (blockIdx.x == 0) {               // zero imp/cnt for this call
    if (tid < NE) imp[tid] = 0.f;
    if (tid == NE) *cnt = 0u;
  }

  const float* __restrict__ xp0 = x + (size_t)(rbase + l15) * NK + k0 + lhi * 8;
  const float* __restrict__ xp1 = xp0 + (size_t)16 * NK;

  // ---- issue first x loads before W conversion (overlap latency) ----
  float4 ca0 = *(const float4*)(xp0);
  float4 ca1 = *(const float4*)(xp0 + 4);
  float4 cb0 = *(const float4*)(xp1);
  float4 cb1 = *(const float4*)(xp1 + 4);
  float4 na0 = *(const float4*)(xp0 + 32);
  float4 na1 = *(const float4*)(xp0 + 36);
  float4 nb0 = *(const float4*)(xp1 + 32);
  float4 nb1 = *(const float4*)(xp1 + 36);

  // ---- W slice -> fragment-linear f16 hi/lo LDS (same math as k_prep) ----
  {
    const int nt   = wv & 3;            // wave handles one nt, 8 k-steps
    const int half = wv >> 2;
    const int e  = nt * 16 + l15;
    const float* __restrict__ wrow = W + (size_t)e * NK + k0 + lhi * 8;
#pragma unroll
    for (int g = 0; g < 8; ++g) {
      const int gk = half * 8 + g;
      const float4 w0 = *(const float4*)(wrow + gk * 32);
      const float4 w1 = *(const float4*)(wrow + gk * 32 + 4);
      f16x8 hi, lo;
      CVT8(hi, lo, w0, w1);
      WH[gk][nt][lane] = hi;
      WL[gk][nt][lane] = lo;
    }
  }
  __syncthreads();

  // ---- GEMM: 16 k-steps of 32; W from LDS, x depth-2 register prefetch ----
  f32x4 acc0[4], acc1[4];
#pragma unroll
  for (int nt = 0; nt < 4; ++nt) {
    acc0[nt] = (f32x4){0.f, 0.f, 0.f, 0.f};
    acc1[nt] = (f32x4){0.f, 0.f, 0.f, 0.f};
  }

#pragma unroll
  for (int ks = 0; ks < 16; ++ks) {
    // x prefetch depth 2
    float4 pa0, pa1, pb0, pb1;
    if (ks + 2 < 16) {
      pa0 = *(const float4*)(xp0 + (ks + 2) * 32);
      pa1 = *(const float4*)(xp0 + (ks + 2) * 32 + 4);
      pb0 = *(const float4*)(xp1 + (ks + 2) * 32);
      pb1 = *(const float4*)(xp1 + (ks + 2) * 32 + 4);
    }
    // W fragments from LDS (conflict-free: lane-linear 16B, 2-way = free)
    f16x8 wh[4], wl[4];
#pragma unroll
    for (int nt = 0; nt < 4; ++nt) {
      wh[nt] = WH[ks][nt][lane];
      wl[nt] = WL[ks][nt][lane];
    }

    f16x8 ah, al, bh, bl;
    CVT8(ah, al, ca0, ca1);
    CVT8(bh, bl, cb0, cb1);

#pragma unroll
    for (int nt = 0; nt < 4; ++nt) {
      acc0[nt] = __builtin_amdgcn_mfma_f32_16x16x32_f16(ah, wh[nt], acc0[nt], 0, 0, 0);
      acc1[nt] = __builtin_amdgcn_mfma_f32_16x16x32_f16(bh, wh[nt], acc1[nt], 0, 0, 0);
    }
#pragma unroll
    for (int nt = 0; nt < 4; ++nt) {
      acc0[nt] = __builtin_amdgcn_mfma_f32_16x16x32_f16(ah, wl[nt], acc0[nt], 0, 0, 0);
      acc1[nt] = __builtin_amdgcn_mfma_f32_16x16x32_f16(bh, wl[nt], acc1[nt], 0, 0, 0);
    }
#pragma unroll
    for (int nt = 0; nt < 4; ++nt) {
      acc0[nt] = __builtin_amdgcn_mfma_f32_16x16x32_f16(al, wh[nt], acc0[nt], 0, 0, 0);
      acc1[nt] = __builtin_amdgcn_mfma_f32_16x16x32_f16(bl, wh[nt], acc1[nt], 0, 0, 0);
    }

    // rotate (fully unrolled -> static)
    ca0 = na0; ca1 = na1; cb0 = nb0; cb1 = nb1;
    na0 = pa0; na1 = pa1; nb0 = pb0; nb1 = pb1;
  }

  // ---- epilogue (round-5 exact): D col = lane&15, row = (lane>>4)*4+reg ----
  float* dst0 = part + ((size_t)seg * NROWS + rbase) * NE;
  float* dst1 = dst0 + (size_t)16 * NE;
#pragma unroll
  for (int nt = 0; nt < 4; ++nt)
#pragma unroll
    for (int r = 0; r < 4; ++r) {
      dst0[(size_t)(lhi * 4 + r) * NE + nt * 16 + l15] = acc0[nt][r];
      dst1[(size_t)(lhi * 4 + r) * NE + nt * 16 + l15] = acc1[nt][r];
    }
}

// ---------------------------------------------------------------------------
// Kernel 2: sum 8 K-segment partials (round-5 verified tree) -> softmax over
// 64 experts -> stable top-2 -> renorm -> outputs; importance atomics; LAST
// block (round-7 verified counter pattern) computes aux loss.
// grid = 256, block = 256 (4 waves), each wave 8 rows.
// ---------------------------------------------------------------------------
__global__ __launch_bounds__(256) void k_soft(const float* __restrict__ part,
                                              float* __restrict__ out,
                                              float* __restrict__ imp,
                                              unsigned* __restrict__ cnt) {
  __shared__ float simp[4][64];
  __shared__ int lastflag;
  const int tid  = threadIdx.x;
  const int lane = tid & 63;
  const int wv   = tid >> 6;
  const int rbase = blockIdx.x * 32 + wv * 8;
  float impacc = 0.f;

  for (int i = 0; i < 8; ++i) {
    const int row = rbase + i;
    float v[NSEG];
#pragma unroll
    for (int s = 0; s < NSEG; ++s)
      v[s] = part[((size_t)s * NROWS + row) * NE + lane];
    const float lg = (((v[0] + v[1]) + (v[2] + v[3])) +
                      ((v[4] + v[5]) + (v[6] + v[7])));

    float m = lg;
#pragma unroll
    for (int d = 1; d < 64; d <<= 1) m = fmaxf(m, __shfl_xor(m, d));
    float p = expf(lg - m);
    float s = p;
#pragma unroll
    for (int d = 1; d < 64; d <<= 1) s += __shfl_xor(s, d);
    const float gate = p / s;
    impacc += gate;

    const unsigned long long key =
        ((unsigned long long)__float_as_uint(gate) << 32) | (unsigned)(63 - lane);
    unsigned long long k1 = key;
#pragma unroll
    for (int d = 1; d < 64; d <<= 1) {
      unsigned long long o = __shfl_xor(k1, d);
      if (o > k1) k1 = o;
    }
    const int e1 = 63 - (int)(k1 & 63ull);
    unsigned long long k2 = (lane == e1) ? 0ull : key;
#pragma unroll
    for (int d = 1; d < 64; d <<= 1) {
      unsigned long long o = __shfl_xor(k2, d);
      if (o > k2) k2 = o;
    }
    const int e2 = 63 - (int)(k2 & 63ull);

    if (lane == 0) {
      const float g1 = __uint_as_float((unsigned)(k1 >> 32));
      const float g2 = __uint_as_float((unsigned)(k2 >> 32));
      const float tt  = expf(g2 - g1);          // g1 >= g2
      const float inv = 1.f / (1.f + tt);
      out[(size_t)row * 2]     = inv;
      out[(size_t)row * 2 + 1] = tt * inv;
      out[(size_t)NROWS * 2 + row * 2]     = (float)e1;
      out[(size_t)NROWS * 2 + row * 2 + 1] = (float)e2;
    }
  }

  simp[wv][lane] = impacc;
  __syncthreads();
  if (tid < NE) {
    const float v = simp[0][tid] + simp[1][tid] + simp[2][tid] + simp[3][tid];
    atomicAdd(&imp[tid], v);
  }
  __syncthreads();                       // this block's imp atomics issued+done

  if (tid == 0) {
    const unsigned old = atomicAdd(cnt, 1u);
    lastflag = (old == 255u) ? 1 : 0;
  }
  __syncthreads();

  if (lastflag && tid < NE) {            // wave 0 only
    const float v = atomicAdd(&imp[tid], 0.f);   // device-scope read
    float s = v;
#pragma unroll
    for (int d = 1; d < 64; d <<= 1) s += __shfl_xor(s, d);
    const float mean = s / 64.f;
    const float dv = v - mean;
    float sq = dv * dv;
#pragma unroll
    for (int d = 1; d < 64; d <<= 1) sq += __shfl_xor(sq, d);
    const float stdv = sqrtf(sq / 63.f);  // unbiased (E-1)
    const float r = stdv / (mean + 1e-6f);
    if (tid == 0) out[(size_t)NROWS * 4] = r * r;  // d_out[32768]
  }
}

// ---------------------------------------------------------------------------
extern "C" void kernel_launch(void* const* d_in, const int* in_sizes, int n_in,
                              void* d_out, int out_size, void* d_ws, size_t ws_size,
                              hipStream_t stream) {
  const float* x = (const float*)d_in[0];
  const float* W = (const float*)d_in[1];
  float* out  = (float*)d_out;
  float* part = (float*)d_ws;                          // 8*8192*64 f32 = 16 MB
  float* imp  = part + (size_t)NSEG * NROWS * NE;      // 64 f32
  unsigned* cnt = (unsigned*)(imp + NE);               // 1 u32

  hipLaunchKernelGGL(k_main, dim3(256), dim3(512), 0, stream, x, W, part, imp, cnt);
  hipLaunchKernelGGL(k_soft, dim3(256), dim3(256), 0, stream, part, out, imp, cnt);
}